// Round 6
// baseline (150.330 us; speedup 1.0000x reference)
//
#include <hip/hip_runtime.h>

#define BB   32
#define SS   100
#define TT   4
#define NCC2 500
#define NC3P 2001
#define DD   128

// k_main LDS float-index layout (GRU role):
//   h[0..128) | part[128..896) | gam[896..996) | rr[996..1096) |
//   W_f16 (uint4-packed) [1152..25728) | h_all [25728..38528)
//   presum temp uses h_all region during preamble.
// scan role uses [0..3204) only.
#define WB    1152
#define HALLN 25728
#define LDSF  38528

typedef _Float16 h2v __attribute__((ext_vector_type(2)));

__device__ __forceinline__ float fast_rcp(float x) { return __builtin_amdgcn_rcpf(x); }
__device__ __forceinline__ float fast_sig(float x) { return fast_rcp(1.f + __expf(-x)); }
__device__ __forceinline__ float fast_tanh(float x) { return 1.f - 2.f * fast_rcp(__expf(2.f * x) + 1.f); }

// Full 64-lane sum via DPP; result valid in lane 63 only.
__device__ __forceinline__ float dpp_sum64(float x) {
    x += __int_as_float(__builtin_amdgcn_update_dpp(0, __float_as_int(x), 0x111, 0xf, 0xf, true)); // row_shr:1
    x += __int_as_float(__builtin_amdgcn_update_dpp(0, __float_as_int(x), 0x112, 0xf, 0xf, true)); // row_shr:2
    x += __int_as_float(__builtin_amdgcn_update_dpp(0, __float_as_int(x), 0x114, 0xf, 0xf, true)); // row_shr:4
    x += __int_as_float(__builtin_amdgcn_update_dpp(0, __float_as_int(x), 0x118, 0xf, 0xf, true)); // row_shr:8
    x += __int_as_float(__builtin_amdgcn_update_dpp(0, __float_as_int(x), 0x142, 0xa, 0xf, true)); // row_bcast:15
    x += __int_as_float(__builtin_amdgcn_update_dpp(0, __float_as_int(x), 0x143, 0xc, 0xf, true)); // row_bcast:31
    return x;
}

// Sum within each group of 16 lanes; result valid in lane 15 of each group.
__device__ __forceinline__ float dpp_sum16(float x) {
    x += __int_as_float(__builtin_amdgcn_update_dpp(0, __float_as_int(x), 0x111, 0xf, 0xf, true));
    x += __int_as_float(__builtin_amdgcn_update_dpp(0, __float_as_int(x), 0x112, 0xf, 0xf, true));
    x += __int_as_float(__builtin_amdgcn_update_dpp(0, __float_as_int(x), 0x114, 0xf, 0xf, true));
    x += __int_as_float(__builtin_amdgcn_update_dpp(0, __float_as_int(x), 0x118, 0xf, 0xf, true));
    return x;
}

__device__ __forceinline__ float dot4(float4 a, float4 b) {
    return fmaf(a.x, b.x, fmaf(a.y, b.y, fmaf(a.z, b.z, a.w * b.w)));
}

// ---------------------------------------------------------------------------
// k_pre: u-vectors for MLP2/MLP3 rank-1 factorization, coalesced.
__global__ __launch_bounds__(64) void k_pre(const float* __restrict__ l2W1,
                                            const float* __restrict__ l3W1,
                                            const float* __restrict__ v_c2,
                                            const float* __restrict__ v_c3,
                                            const float* __restrict__ v_d,
                                            const float* __restrict__ Remb,
                                            float* __restrict__ ws)
{
    const int t = threadIdx.x;
    const int g = t >> 4;
    const int c = (t & 15) * 8;
    const float* vsrc = (g == 0) ? v_c2 : (g == 1) ? v_c3 : (g == 2) ? v_d : Remb;
    const float4 va  = *(const float4*)(vsrc + c);
    const float4 vb  = *(const float4*)(vsrc + c + 4);
    const float4 va1 = *(const float4*)(Remb + 128 + c);
    const float4 vb1 = *(const float4*)(Remb + 132 + c);
#pragma unroll
    for (int r = 0; r < 8; ++r) {
        const int row_id = blockIdx.x * 8 + r;       // 0..255
        const float* W = (row_id < 128) ? l2W1 : l3W1;
        float* U = ws + ((row_id < 128) ? 0 : 640);
        const int i = row_id & 127;
        const float* wr = W + i * 512 + g * 128 + c;
        const float4 w0 = *(const float4*)(wr);
        const float4 w1 = *(const float4*)(wr + 4);
        float p  = dot4(w0, va)  + dot4(w1, vb);
        float p1 = dot4(w0, va1) + dot4(w1, vb1);
        p  = dpp_sum16(p);
        p1 = dpp_sum16(p1);
        if ((t & 15) == 15) {
            U[g * 128 + i] = p;
            if (g == 3) U[512 + i] = p1;
        }
    }
}

// ---------------------------------------------------------------------------
// blocks 0..31  : GRU (768 thr, k-split x2, W_hh f16-packed in LDS, fma_mix)
// blocks 32..159: scan, 4 blocks per batch (full recurrence each; snapshot
//                 stores split 4 ways to spread per-CU HBM write drain)
__global__ __launch_bounds__(768, 1) void k_main(
    const int* __restrict__ c2_seq, const int* __restrict__ c3_seq,
    const int* __restrict__ d_seq,  const int* __restrict__ r_seq,
    const float* __restrict__ D_emb, const float* __restrict__ Remb,
    const float* __restrict__ v_d,
    const float* __restrict__ W_ih, const float* __restrict__ W_hh,
    const float* __restrict__ b_ih, const float* __restrict__ b_hh,
    const float* __restrict__ l2b1, const float* __restrict__ l2W2, const float* __restrict__ l2b2,
    const float* __restrict__ l3b1, const float* __restrict__ l3W2, const float* __restrict__ l3b2,
    const float* __restrict__ ws, float* __restrict__ h_out,
    float* __restrict__ C2o, float* __restrict__ C3o)
{
    __shared__ __align__(16) float sh[LDSF];
    int* shi = (int*)sh;
    const int blk = blockIdx.x;
    const int t = threadIdx.x;

    if (blk < BB) {
        // =============== GRU role ===============
        const int b  = blk;
        const int wv = t >> 6;          // wave 0..11
        const int l  = t & 63;
        const int p  = (t >= 384) ? 1 : 0;
        const int j  = t - p * 384;
        const int p16 = p * 16;

        // ---- stage W_hh (rows j, k-half p) as f16 pairs into LDS ----
        uint4* wl = reinterpret_cast<uint4*>(sh + WB);
        {
            const float4* wr4 = (const float4*)(W_hh + j * DD + p * 64);
#pragma unroll
            for (int i = 0; i < 8; ++i) {
                float4 A = wr4[2 * i], B = wr4[2 * i + 1];
                uint4 u;
                u.x = __builtin_bit_cast(unsigned int, __builtin_amdgcn_cvt_pkrtz(A.x, A.y));
                u.y = __builtin_bit_cast(unsigned int, __builtin_amdgcn_cvt_pkrtz(A.z, A.w));
                u.z = __builtin_bit_cast(unsigned int, __builtin_amdgcn_cvt_pkrtz(B.x, B.y));
                u.w = __builtin_bit_cast(unsigned int, __builtin_amdgcn_cvt_pkrtz(B.z, B.w));
                wl[(wv * 8 + i) * 64 + l] = u;
            }
        }

        // ---- input-projection partials (W_ih dot v_d / Remb rows) ----
        float pd = 0.f, pr0 = 0.f, pr1 = 0.f;
        {
            const float4* wd4 = (const float4*)(W_ih + j * 256 + p * 64);
            const float4* wr4 = (const float4*)(W_ih + j * 256 + 128 + p * 64);
            const float4* vd4 = (const float4*)(v_d + p * 64);
            const float4* r04 = (const float4*)(Remb + p * 64);
            const float4* r14 = (const float4*)(Remb + 128 + p * 64);
#pragma unroll
            for (int k4 = 0; k4 < 16; ++k4) {
                const float4 wd = wd4[k4], wr = wr4[k4];
                const float4 vd = vd4[k4], r0 = r04[k4], r1 = r14[k4];
                pd  = fmaf(wd.x, vd.x, fmaf(wd.y, vd.y, fmaf(wd.z, vd.z, fmaf(wd.w, vd.w, pd))));
                pr0 = fmaf(wr.x, r0.x, fmaf(wr.y, r0.y, fmaf(wr.z, r0.z, fmaf(wr.w, r0.w, pr0))));
                pr1 = fmaf(wr.x, r1.x, fmaf(wr.y, r1.y, fmaf(wr.z, r1.z, fmaf(wr.w, r1.w, pr1))));
            }
        }
        // presum temp lives in the (still unused) h_all region
        sh[HALLN + t] = pd; sh[HALLN + 768 + t] = pr0; sh[HALLN + 1536 + t] = pr1;
        if (t < DD) sh[t] = 0.f;   // h0
        if (t < SS) {
            sh[896 + t]  = D_emb[d_seq[b * SS + t]];
            shi[996 + t] = r_seq[b * SS + t];
        }
        __syncthreads();

        float gd_r=0,gd_z=0,gd_n=0, g0_r=0,g0_z=0,g0_n=0, g1_r=0,g1_z=0,g1_n=0;
        float bi_r=0,bi_z=0,bi_n=0, bh_r=0,bh_z=0,bh_n=0, h = 0.f;
        if (t < DD) {
            gd_r = sh[HALLN+t]        + sh[HALLN+t+384];
            gd_z = sh[HALLN+t+128]    + sh[HALLN+t+512];
            gd_n = sh[HALLN+t+256]    + sh[HALLN+t+640];
            g0_r = sh[HALLN+768+t]     + sh[HALLN+768+t+384];
            g0_z = sh[HALLN+768+t+128] + sh[HALLN+768+t+512];
            g0_n = sh[HALLN+768+t+256] + sh[HALLN+768+t+640];
            g1_r = sh[HALLN+1536+t]     + sh[HALLN+1536+t+384];
            g1_z = sh[HALLN+1536+t+128] + sh[HALLN+1536+t+512];
            g1_n = sh[HALLN+1536+t+256] + sh[HALLN+1536+t+640];
            bi_r = b_ih[t]; bi_z = b_ih[t+128]; bi_n = b_ih[t+256];
            bh_r = b_hh[t]; bh_z = b_hh[t+128]; bh_n = b_hh[t+256];
        }
        __syncthreads();

        const uint4* wlr = wl;
        for (int s = 0; s < SS; ++s) {
            float a0 = 0.f, a1 = 0.f, a2 = 0.f, a3 = 0.f;
            const float4* hv4 = reinterpret_cast<const float4*>(sh);
#pragma unroll
            for (int i = 0; i < 8; ++i) {
                uint4 q = wlr[(wv * 8 + i) * 64 + l];
                float4 ha = hv4[p16 + 2 * i];
                float4 hb = hv4[p16 + 2 * i + 1];
                h2v w01 = __builtin_bit_cast(h2v, q.x);
                h2v w23 = __builtin_bit_cast(h2v, q.y);
                h2v w45 = __builtin_bit_cast(h2v, q.z);
                h2v w67 = __builtin_bit_cast(h2v, q.w);
                a0 = fmaf((float)w01.x, ha.x, a0); a1 = fmaf((float)w01.y, ha.y, a1);
                a2 = fmaf((float)w23.x, ha.z, a2); a3 = fmaf((float)w23.y, ha.w, a3);
                a0 = fmaf((float)w45.x, hb.x, a0); a1 = fmaf((float)w45.y, hb.y, a1);
                a2 = fmaf((float)w67.x, hb.z, a2); a3 = fmaf((float)w67.y, hb.w, a3);
            }
            sh[128 + t] = (a0 + a1) + (a2 + a3);
            __syncthreads();
            if (t < DD) {
                float ghr = sh[128+t]     + sh[128+t+384] + bh_r;
                float ghz = sh[128+t+128] + sh[128+t+512] + bh_z;
                float ghn = sh[128+t+256] + sh[128+t+640] + bh_n;
                float gamma = sh[896 + s]; int rr = shi[996 + s];
                float gir = fmaf(gamma, gd_r, (rr ? g1_r : g0_r) + bi_r);
                float giz = fmaf(gamma, gd_z, (rr ? g1_z : g0_z) + bi_z);
                float gin = fmaf(gamma, gd_n, (rr ? g1_n : g0_n) + bi_n);
                float r = fast_sig(gir + ghr);
                float z = fast_sig(giz + ghz);
                float n = fast_tanh(fmaf(r, ghn, gin));
                h = (1.f - z) * n + z * h;
                sh[t] = h;
                sh[HALLN + s * DD + t] = h;
            }
            __syncthreads();
        }

        // ---- bulk h_out writeback ----
        {
            const float4* hsrc = reinterpret_cast<const float4*>(sh + HALLN);
            float4* hdst = reinterpret_cast<float4*>(h_out + (size_t)b * SS * DD);
            for (int i = t; i < SS * DD / 4; i += 768) hdst[i] = hsrc[i];
        }
    } else if (t < 64) {
        // =============== scan role (single wave; 4 blocks per batch) ===============
        const int b = (blk - BB) >> 2;
        const int q = (blk - BB) & 3;
        float* C2s = sh;
        float* C3s = sh + NCC2;
        for (int k = t; k < NCC2 + NC3P; k += 64) sh[k] = 0.f;
        for (int k = t; k < SS; k += 64) {
            shi[2501 + k] = c2_seq[b * SS + k];
            sh[3004 + k]  = D_emb[d_seq[b * SS + k]];
            shi[3104 + k] = r_seq[b * SS + k];
        }
        for (int k = t; k < SS; k += 64)
            reinterpret_cast<int4*>(shi + 2604)[k] = reinterpret_cast<const int4*>(c3_seq + b * SS * TT)[k];

        const float* u2 = ws;
        const float* u3 = ws + 640;
        const float u2a0 = u2[t],        u2a1 = u2[64 + t];
        const float u2b0 = u2[128 + t],  u2b1 = u2[192 + t];
        const float u2c0 = u2[256 + t],  u2c1 = u2[320 + t];
        const float u2d00 = u2[384 + t], u2d01 = u2[448 + t];
        const float u2d10 = u2[512 + t], u2d11 = u2[576 + t];
        const float u3a0 = u3[t],        u3a1 = u3[64 + t];
        const float u3b0 = u3[128 + t],  u3b1 = u3[192 + t];
        const float u3c0 = u3[256 + t],  u3c1 = u3[320 + t];
        const float u3d00 = u3[384 + t], u3d01 = u3[448 + t];
        const float u3d10 = u3[512 + t], u3d11 = u3[576 + t];
        const float b2_0 = l2b1[t], b2_1 = l2b1[64 + t];
        const float w2_0 = l2W2[t], w2_1 = l2W2[64 + t];
        const float b3_0 = l3b1[t], b3_1 = l3b1[64 + t];
        const float w3_0 = l3W2[t], w3_1 = l3W2[64 + t];
        const float c2bias = l2b2[0], c3bias = l3b2[0];

        int  nc2 = shi[2501];
        int4 nc3 = reinterpret_cast<const int4*>(shi + 2604)[0];
        float ngam = sh[3004];
        int   nrr  = shi[3104];

        for (int s = 0; s < SS; ++s) {
            const int rs = b * SS + s;
            const int c2i = nc2;
            const int i0 = nc3.x, i1 = nc3.y, i2 = nc3.z, i3 = nc3.w;
            const float gamma = ngam;
            const int rr = nrr;
            if (s + 1 < SS) {
                nc2 = shi[2501 + s + 1];
                nc3 = reinterpret_cast<const int4*>(shi + 2604)[s + 1];
                ngam = sh[3004 + s + 1];
                nrr  = shi[3104 + s + 1];
            }

            const float beta2 = C2s[c2i];
            const bool k0 = (i0 != 0), k1 = (i1 != 0), k2 = (i2 != 0), k3 = (i3 != 0);
            const float m0 = k0 ? 1.f : 0.f, m1 = k1 ? 1.f : 0.f;
            const float m2 = k2 ? 1.f : 0.f, m3 = k3 ? 1.f : 0.f;
            const float bt0 = C3s[i0], bt1 = C3s[i1], bt2 = C3s[i2], bt3 = C3s[i3];
            const float msum = m0 + m1 + m2 + m3;
            const float b3bar = (bt0 * m0 + bt1 * m1 + bt2 * m2 + bt3 * m3) * fast_rcp(msum);

            const float ud20 = rr ? u2d10 : u2d00, ud21 = rr ? u2d11 : u2d01;
            const float ud30 = rr ? u3d10 : u3d00, ud31 = rr ? u3d11 : u3d01;

            float h20 = fmaf(beta2, u2a0, fmaf(b3bar, u2b0, fmaf(gamma, u2c0, ud20 + b2_0)));
            float h21 = fmaf(beta2, u2a1, fmaf(b3bar, u2b1, fmaf(gamma, u2c1, ud21 + b2_1)));
            float newc2 = dpp_sum64(fmaf(fmaxf(h20, 0.f), w2_0, fmaxf(h21, 0.f) * w2_1)) + c2bias;

            const float base30 = fmaf(beta2, u3a0, fmaf(gamma, u3c0, ud30 + b3_0));
            const float base31 = fmaf(beta2, u3a1, fmaf(gamma, u3c1, ud31 + b3_1));
            float ha, hb, q0, q1, q2, q3;
            ha = fmaf(bt0, u3b0, base30); hb = fmaf(bt0, u3b1, base31);
            q0 = dpp_sum64(fmaf(fmaxf(ha, 0.f), w3_0, fmaxf(hb, 0.f) * w3_1)) + c3bias;
            ha = fmaf(bt1, u3b0, base30); hb = fmaf(bt1, u3b1, base31);
            q1 = dpp_sum64(fmaf(fmaxf(ha, 0.f), w3_0, fmaxf(hb, 0.f) * w3_1)) + c3bias;
            ha = fmaf(bt2, u3b0, base30); hb = fmaf(bt2, u3b1, base31);
            q2 = dpp_sum64(fmaf(fmaxf(ha, 0.f), w3_0, fmaxf(hb, 0.f) * w3_1)) + c3bias;
            ha = fmaf(bt3, u3b0, base30); hb = fmaf(bt3, u3b1, base31);
            q3 = dpp_sum64(fmaf(fmaxf(ha, 0.f), w3_0, fmaxf(hb, 0.f) * w3_1)) + c3bias;

            float val0, val1, val2, val3;
            {
                float c = m0 + ((k1 && i1 == i0) ? 1.f : 0.f) + ((k2 && i2 == i0) ? 1.f : 0.f) + ((k3 && i3 == i0) ? 1.f : 0.f);
                float qs = (k0 ? q0 : 0.f) + ((k1 && i1 == i0) ? q1 : 0.f) + ((k2 && i2 == i0) ? q2 : 0.f) + ((k3 && i3 == i0) ? q3 : 0.f);
                val0 = bt0 * (1.f - c) + qs;
            }
            {
                float c = ((k0 && i0 == i1) ? 1.f : 0.f) + m1 + ((k2 && i2 == i1) ? 1.f : 0.f) + ((k3 && i3 == i1) ? 1.f : 0.f);
                float qs = ((k0 && i0 == i1) ? q0 : 0.f) + (k1 ? q1 : 0.f) + ((k2 && i2 == i1) ? q2 : 0.f) + ((k3 && i3 == i1) ? q3 : 0.f);
                val1 = bt1 * (1.f - c) + qs;
            }
            {
                float c = ((k0 && i0 == i2) ? 1.f : 0.f) + ((k1 && i1 == i2) ? 1.f : 0.f) + m2 + ((k3 && i3 == i2) ? 1.f : 0.f);
                float qs = ((k0 && i0 == i2) ? q0 : 0.f) + ((k1 && i1 == i2) ? q1 : 0.f) + (k2 ? q2 : 0.f) + ((k3 && i3 == i2) ? q3 : 0.f);
                val2 = bt2 * (1.f - c) + qs;
            }
            {
                float c = ((k0 && i0 == i3) ? 1.f : 0.f) + ((k1 && i1 == i3) ? 1.f : 0.f) + ((k2 && i2 == i3) ? 1.f : 0.f) + m3;
                float qs = ((k0 && i0 == i3) ? q0 : 0.f) + ((k1 && i1 == i3) ? q1 : 0.f) + ((k2 && i2 == i3) ? q2 : 0.f) + (k3 ? q3 : 0.f);
                val3 = bt3 * (1.f - c) + qs;
            }

            if (t == 63) {
                C2s[c2i] = newc2;
                if (k0) C3s[i0] = val0;
                if (k1) C3s[i1] = val1;
                if (k2) C3s[i2] = val2;
                if (k3) C3s[i3] = val3;
            }

            // ---- snapshot store: this block's quarter of row (b,s) ----
            if (q == 0) {
                float* c2row = C2o + (size_t)rs * NCC2;   // 500 = 4*125, always 16B aligned
                const float4* src = reinterpret_cast<const float4*>(C2s);
                float4* dst = reinterpret_cast<float4*>(c2row);
                dst[t] = src[t];
                if (t < 61) dst[64 + t] = src[64 + t];
            } else {
                float* c3row = C3o + (size_t)rs * NC3P;
                const int lo = (q - 1) * 667;
                const int n = 667;
                int pre = (4 - (int)(((unsigned)(rs * NC3P + lo)) & 3)) & 3;
                if (pre > n) pre = n;
                if (t < pre) c3row[lo + t] = C3s[lo + t];
                const int st = lo + pre;
                const int rem = n - pre;
                const int nv = rem >> 2, tl = rem & 3;
                for (int i = t; i < nv; i += 64) {
                    const int d = st + 4 * i;
                    *reinterpret_cast<float4*>(c3row + d) =
                        make_float4(C3s[d], C3s[d + 1], C3s[d + 2], C3s[d + 3]);
                }
                if (t < tl) {
                    const int d = st + 4 * nv + t;
                    c3row[d] = C3s[d];
                }
            }
        }
    }
}

// ---------------------------------------------------------------------------
// k_alpha: alpha = MLP1(h). 200 blocks x 256 threads, 16 rows per block.
// W1 staged ONCE into LDS (XOR-swizzled), 16 row-accumulators in registers.
__global__ __launch_bounds__(256) void k_alpha(const float* __restrict__ h_seq,
                                               const float* __restrict__ W1,
                                               const float* __restrict__ b1,
                                               const float* __restrict__ W2,
                                               const float* __restrict__ b2,
                                               float* __restrict__ alpha)
{
    // floats: h[0,2048) | part[2048,6144) | W[6144,22528) | red[22528,22560)
    __shared__ __align__(16) float sl[22560];
    const int t = threadIdx.x;
    const int base = blockIdx.x * 16;

    float4* hl4 = reinterpret_cast<float4*>(sl);
    const float4* hg = reinterpret_cast<const float4*>(h_seq + (size_t)base * DD);
    for (int i = t; i < 512; i += 256) hl4[i] = hg[i];

    float4* wl4 = reinterpret_cast<float4*>(sl + 6144);
    const float4* wg = reinterpret_cast<const float4*>(W1);
    for (int g = t; g < 4096; g += 256) {
        const int ch = g >> 5, k4 = g & 31;
        wl4[ch * 32 + (k4 ^ (ch & 31))] = wg[g];
    }
    __syncthreads();

    const int ch = t & 127, half = t >> 7;
    float acc[16];
#pragma unroll
    for (int r = 0; r < 16; ++r) acc[r] = 0.f;
#pragma unroll
    for (int kk = 0; kk < 16; ++kk) {
        const int k4 = half * 16 + kk;
        const float4 w = wl4[ch * 32 + (k4 ^ (ch & 31))];
#pragma unroll
        for (int r = 0; r < 16; ++r) {
            const float4 hv = hl4[r * 32 + k4];
            acc[r] = fmaf(w.x, hv.x, fmaf(w.y, hv.y, fmaf(w.z, hv.z, fmaf(w.w, hv.w, acc[r]))));
        }
    }
#pragma unroll
    for (int r = 0; r < 16; ++r) sl[2048 + r * 256 + t] = acc[r];
    __syncthreads();
    if (t < 128) {
        const float b1v = b1[t], w2v = W2[t];
#pragma unroll
        for (int r = 0; r < 16; ++r) {
            float v = fmaxf(sl[2048 + r * 256 + t] + sl[2048 + r * 256 + 128 + t] + b1v, 0.f) * w2v;
            v = dpp_sum64(v);
            if ((t & 63) == 63) sl[22528 + r * 2 + (t >> 6)] = v;
        }
    }
    __syncthreads();
    if (t < 16) alpha[base + t] = sl[22528 + 2 * t] + sl[22528 + 2 * t + 1] + b2[0];
}

// ---------------------------------------------------------------------------
extern "C" void kernel_launch(void* const* d_in, const int* in_sizes, int n_in,
                              void* d_out, int out_size, void* d_ws, size_t ws_size,
                              hipStream_t stream)
{
    (void)in_sizes; (void)n_in; (void)out_size; (void)ws_size;
    const int*   c2_seq = (const int*)d_in[0];
    const int*   c3_seq = (const int*)d_in[1];
    const int*   d_seq  = (const int*)d_in[2];
    const int*   r_seq  = (const int*)d_in[3];
    const float* D_emb  = (const float*)d_in[4];
    const float* Remb   = (const float*)d_in[5];
    const float* v_c2   = (const float*)d_in[6];
    const float* v_c3   = (const float*)d_in[7];
    const float* v_d    = (const float*)d_in[8];
    const float* W_ih   = (const float*)d_in[9];
    const float* W_hh   = (const float*)d_in[10];
    const float* b_ih   = (const float*)d_in[11];
    const float* b_hh   = (const float*)d_in[12];
    const float* l1W1   = (const float*)d_in[13];
    const float* l1b1   = (const float*)d_in[14];
    const float* l1W2   = (const float*)d_in[15];
    const float* l1b2   = (const float*)d_in[16];
    const float* l2W1   = (const float*)d_in[17];
    const float* l2b1   = (const float*)d_in[18];
    const float* l2W2   = (const float*)d_in[19];
    const float* l2b2   = (const float*)d_in[20];
    const float* l3W1   = (const float*)d_in[21];
    const float* l3b1   = (const float*)d_in[22];
    const float* l3W2   = (const float*)d_in[23];
    const float* l3b2   = (const float*)d_in[24];

    float* out   = (float*)d_out;
    float* alpha = out;                 // [B,S]
    float* h_out = out + 3200;          // [B,S,128]
    float* C2o   = out + 412800;        // [B,S,500]
    float* C3o   = out + 2012800;       // [B,S,2001]
    float* ws    = (float*)d_ws;

    k_pre<<<32, 64, 0, stream>>>(l2W1, l3W1, v_c2, v_c3, v_d, Remb, ws);
    k_main<<<BB + 4 * BB, 768, 0, stream>>>(c2_seq, c3_seq, d_seq, r_seq, D_emb, Remb, v_d,
                                            W_ih, W_hh, b_ih, b_hh,
                                            l2b1, l2W2, l2b2, l3b1, l3W2, l3b2,
                                            ws, h_out, C2o, C3o);
    k_alpha<<<200, 256, 0, stream>>>(h_out, l1W1, l1b1, l1W2, l1b2, alpha);
}

// Round 7
// 112.679 us; speedup vs baseline: 1.3341x; 1.3341x over previous
//
#include <hip/hip_runtime.h>

#define BB   32
#define SS   100
#define TT   4
#define NCC2 500
#define NC3P 2001
#define DD   128

// k_main LDS float-index layout
//  GRU : h[0..128) | part[128..1664) (=[j*4+p4], 384x4) | gam[1664..1764) |
//        rr[1764..1864) | h_all[1864..14664)
//        (preamble partials pd/pr0/pr1 reuse [1864..6472) before h_all is written)
//  scan: C2s[0..500) | C3s[500..2501) | tc2[2504..2604) | tc3[2604..3004) |
//        tgam[3004..3104) | trr[3104..3204) | U2[3264..3904) | U3[3904..4544)
#define LDSF 14664

typedef _Float16 h2v __attribute__((ext_vector_type(2)));

__device__ __forceinline__ float fast_rcp(float x) { return __builtin_amdgcn_rcpf(x); }
__device__ __forceinline__ float fast_sig(float x) { return fast_rcp(1.f + __expf(-x)); }
__device__ __forceinline__ float fast_tanh(float x) { return 1.f - 2.f * fast_rcp(__expf(2.f * x) + 1.f); }

__device__ __forceinline__ float dpp_sum64(float x) {
    x += __int_as_float(__builtin_amdgcn_update_dpp(0, __float_as_int(x), 0x111, 0xf, 0xf, true));
    x += __int_as_float(__builtin_amdgcn_update_dpp(0, __float_as_int(x), 0x112, 0xf, 0xf, true));
    x += __int_as_float(__builtin_amdgcn_update_dpp(0, __float_as_int(x), 0x114, 0xf, 0xf, true));
    x += __int_as_float(__builtin_amdgcn_update_dpp(0, __float_as_int(x), 0x118, 0xf, 0xf, true));
    x += __int_as_float(__builtin_amdgcn_update_dpp(0, __float_as_int(x), 0x142, 0xa, 0xf, true));
    x += __int_as_float(__builtin_amdgcn_update_dpp(0, __float_as_int(x), 0x143, 0xc, 0xf, true));
    return x;
}

__device__ __forceinline__ float dpp_sum16(float x) {
    x += __int_as_float(__builtin_amdgcn_update_dpp(0, __float_as_int(x), 0x111, 0xf, 0xf, true));
    x += __int_as_float(__builtin_amdgcn_update_dpp(0, __float_as_int(x), 0x112, 0xf, 0xf, true));
    x += __int_as_float(__builtin_amdgcn_update_dpp(0, __float_as_int(x), 0x114, 0xf, 0xf, true));
    x += __int_as_float(__builtin_amdgcn_update_dpp(0, __float_as_int(x), 0x118, 0xf, 0xf, true));
    return x;
}

__device__ __forceinline__ float dot4(float4 a, float4 b) {
    return fmaf(a.x, b.x, fmaf(a.y, b.y, fmaf(a.z, b.z, a.w * b.w)));
}

__device__ __forceinline__ unsigned pk16(float a, float b) {
    return __builtin_bit_cast(unsigned, __builtin_amdgcn_cvt_pkrtz(a, b));
}
__device__ __forceinline__ uint4 packf16(float4 A, float4 B) {
    uint4 u;
    u.x = pk16(A.x, A.y); u.y = pk16(A.z, A.w);
    u.z = pk16(B.x, B.y); u.w = pk16(B.z, B.w);
    return u;
}

// acc += f16x8(q) dot f32x8(u,v)  — compiler emits v_fma_mix
#define MIX8(q, u, v, acc) do {                                             \
    h2v _x;                                                                 \
    _x = __builtin_bit_cast(h2v, (q).x);                                    \
    acc = fmaf((float)_x.x, (u).x, acc); acc = fmaf((float)_x.y, (u).y, acc);\
    _x = __builtin_bit_cast(h2v, (q).y);                                    \
    acc = fmaf((float)_x.x, (u).z, acc); acc = fmaf((float)_x.y, (u).w, acc);\
    _x = __builtin_bit_cast(h2v, (q).z);                                    \
    acc = fmaf((float)_x.x, (v).x, acc); acc = fmaf((float)_x.y, (v).y, acc);\
    _x = __builtin_bit_cast(h2v, (q).w);                                    \
    acc = fmaf((float)_x.x, (v).z, acc); acc = fmaf((float)_x.y, (v).w, acc);\
} while (0)

// ---------------------------------------------------------------------------
// blocks 0..31  : GRU. 768 thr: thread = (row-pair j2, j2+192; k-quarter p4),
//                 W_hh f16 in 8 named uint4 (32 VGPR). Matvec: 8 broadcast
//                 b128 h-reads + 64 fma_mix. Gates on t<128. h_all in LDS.
// blocks 32..159: scan (4 per batch). All 12 waves first compute the u-vectors
//                 (coalesced, dpp16) into LDS, then wave 0 runs the recurrence
//                 with fused quarter-split snapshot stores.
__global__ __launch_bounds__(768, 1) void k_main(
    const int* __restrict__ c2_seq, const int* __restrict__ c3_seq,
    const int* __restrict__ d_seq,  const int* __restrict__ r_seq,
    const float* __restrict__ D_emb, const float* __restrict__ Remb,
    const float* __restrict__ v_c2, const float* __restrict__ v_c3,
    const float* __restrict__ v_d,
    const float* __restrict__ W_ih, const float* __restrict__ W_hh,
    const float* __restrict__ b_ih, const float* __restrict__ b_hh,
    const float* __restrict__ l2W1, const float* __restrict__ l2b1,
    const float* __restrict__ l2W2, const float* __restrict__ l2b2,
    const float* __restrict__ l3W1, const float* __restrict__ l3b1,
    const float* __restrict__ l3W2, const float* __restrict__ l3b2,
    float* __restrict__ h_out, float* __restrict__ C2o, float* __restrict__ C3o)
{
    __shared__ __align__(16) float sh[LDSF];
    int* shi = (int*)sh;
    float4* sh4 = (float4*)sh;
    const int blk = blockIdx.x;
    const int t = threadIdx.x;

    if (blk < BB) {
        // =============== GRU role ===============
        const int b  = blk;
        const int w  = t >> 6, l = t & 63;
        const int p4 = w & 3;                 // k-quarter 0..3
        const int j2 = (w >> 2) * 64 + l;     // 0..191
        const int jA = j2, jB = j2 + 192;
        const int kb = p4 * 32;

        // ---- W_hh rows jA,jB / quarter kb -> f16, 8 named uint4 (32 VGPR) ----
        uint4 wa0, wa1, wa2, wa3, wb0, wb1, wb2, wb3;
        {
            const float4* ra = (const float4*)(W_hh + jA * DD + kb);
            const float4* rb = (const float4*)(W_hh + jB * DD + kb);
            wa0 = packf16(ra[0], ra[1]); wa1 = packf16(ra[2], ra[3]);
            wa2 = packf16(ra[4], ra[5]); wa3 = packf16(ra[6], ra[7]);
            wb0 = packf16(rb[0], rb[1]); wb1 = packf16(rb[2], rb[3]);
            wb2 = packf16(rb[4], rb[5]); wb3 = packf16(rb[6], rb[7]);
        }

        // ---- input-projection partials over this k-quarter, rows jA, jB ----
        {
            const float4* vd4 = (const float4*)(v_d + kb);
            const float4* r04 = (const float4*)(Remb + kb);
            const float4* r14 = (const float4*)(Remb + 128 + kb);
#pragma unroll
            for (int rr2 = 0; rr2 < 2; ++rr2) {
                const int j = rr2 ? jB : jA;
                const float4* wx = (const float4*)(W_ih + j * 256 + kb);
                const float4* wr = (const float4*)(W_ih + j * 256 + 128 + kb);
                float pd = 0.f, pr0 = 0.f, pr1 = 0.f;
#pragma unroll
                for (int i = 0; i < 8; ++i) {
                    float4 a = wx[i], c = wr[i];
                    float4 vd = vd4[i], r0 = r04[i], r1 = r14[i];
                    pd  = fmaf(a.x, vd.x, fmaf(a.y, vd.y, fmaf(a.z, vd.z, fmaf(a.w, vd.w, pd))));
                    pr0 = fmaf(c.x, r0.x, fmaf(c.y, r0.y, fmaf(c.z, r0.z, fmaf(c.w, r0.w, pr0))));
                    pr1 = fmaf(c.x, r1.x, fmaf(c.y, r1.y, fmaf(c.z, r1.z, fmaf(c.w, r1.w, pr1))));
                }
                sh[1864 + j * 4 + p4] = pd;
                sh[3400 + j * 4 + p4] = pr0;
                sh[4936 + j * 4 + p4] = pr1;
            }
        }
        if (t < SS) {
            sh[1664 + t]  = D_emb[d_seq[b * SS + t]];
            shi[1764 + t] = r_seq[b * SS + t];
        }
        __syncthreads();

        // ---- per-channel constants into registers (t<128) ----
        float gd_r=0,gd_z=0,gd_n=0, g0_r=0,g0_z=0,g0_n=0, g1_r=0,g1_z=0,g1_n=0;
        float bi_r=0,bi_z=0,bi_n=0, bh_r=0,bh_z=0,bh_n=0, h = 0.f;
        if (t < DD) {
            float4 a;
            a = sh4[466 + t];        gd_r = (a.x+a.y)+(a.z+a.w);
            a = sh4[466 + 128 + t];  gd_z = (a.x+a.y)+(a.z+a.w);
            a = sh4[466 + 256 + t];  gd_n = (a.x+a.y)+(a.z+a.w);
            a = sh4[850 + t];        g0_r = (a.x+a.y)+(a.z+a.w);
            a = sh4[850 + 128 + t];  g0_z = (a.x+a.y)+(a.z+a.w);
            a = sh4[850 + 256 + t];  g0_n = (a.x+a.y)+(a.z+a.w);
            a = sh4[1234 + t];       g1_r = (a.x+a.y)+(a.z+a.w);
            a = sh4[1234 + 128 + t]; g1_z = (a.x+a.y)+(a.z+a.w);
            a = sh4[1234 + 256 + t]; g1_n = (a.x+a.y)+(a.z+a.w);
            bi_r = b_ih[t]; bi_z = b_ih[t+128]; bi_n = b_ih[t+256];
            bh_r = b_hh[t]; bh_z = b_hh[t+128]; bh_n = b_hh[t+256];
            sh[t] = 0.f;   // h0
        }
        __syncthreads();

        for (int s = 0; s < SS; ++s) {
            // matvec: 8 broadcast b128 h-reads + 64 fma_mix, 2 part writes
            float aA = 0.f, aB = 0.f;
            {
                const float4* hq = sh4 + p4 * 8;
                float4 h0 = hq[0], h1 = hq[1], h2 = hq[2], h3 = hq[3];
                float4 h4 = hq[4], h5 = hq[5], h6 = hq[6], h7 = hq[7];
                MIX8(wa0, h0, h1, aA); MIX8(wa1, h2, h3, aA);
                MIX8(wa2, h4, h5, aA); MIX8(wa3, h6, h7, aA);
                MIX8(wb0, h0, h1, aB); MIX8(wb1, h2, h3, aB);
                MIX8(wb2, h4, h5, aB); MIX8(wb3, h6, h7, aB);
            }
            sh[128 + jA * 4 + p4] = aA;
            sh[128 + jB * 4 + p4] = aB;
            __syncthreads();
            if (t < DD) {
                float4 q0 = sh4[32 + t];
                float4 q1 = sh4[32 + 128 + t];
                float4 q2 = sh4[32 + 256 + t];
                float ghr = (q0.x+q0.y)+(q0.z+q0.w) + bh_r;
                float ghz = (q1.x+q1.y)+(q1.z+q1.w) + bh_z;
                float ghn = (q2.x+q2.y)+(q2.z+q2.w) + bh_n;
                float gamma = sh[1664 + s]; int rr = shi[1764 + s];
                float gir = fmaf(gamma, gd_r, (rr ? g1_r : g0_r) + bi_r);
                float giz = fmaf(gamma, gd_z, (rr ? g1_z : g0_z) + bi_z);
                float gin = fmaf(gamma, gd_n, (rr ? g1_n : g0_n) + bi_n);
                float r = fast_sig(gir + ghr);
                float z = fast_sig(giz + ghz);
                float n = fast_tanh(fmaf(r, ghn, gin));
                h = (1.f - z) * n + z * h;
                sh[t] = h;
                sh[1864 + s * DD + t] = h;
            }
            __syncthreads();
        }

        // ---- bulk h_out writeback ----
        {
            const float4* hs = (const float4*)(sh + 1864);
            float4* hd = (float4*)(h_out + (size_t)b * SS * DD);
            for (int i = t; i < SS * DD / 4; i += 768) hd[i] = hs[i];
        }
    } else {
        // =============== scan role ===============
        const int sb = blk - BB;
        const int b = sb >> 2;
        const int q = sb & 3;

        // ---- fused u-vector precompute: all 12 waves, coalesced ----
        {
            const int g = (t & 63) >> 4, c8 = ((t & 63) & 15) * 8;
            const float* vsrc = (g == 0) ? v_c2 : (g == 1) ? v_c3 : (g == 2) ? v_d : Remb;
            const float4 va  = *(const float4*)(vsrc + c8);
            const float4 vb  = *(const float4*)(vsrc + c8 + 4);
            const float4 va1 = *(const float4*)(Remb + 128 + c8);
            const float4 vb1 = *(const float4*)(Remb + 132 + c8);
            for (int r = t >> 6; r < 256; r += 12) {
                const float* W = (r < 128) ? l2W1 : l3W1;
                float* U = sh + ((r < 128) ? 3264 : 3904);
                const int i = r & 127;
                const float* wr = W + i * 512 + g * 128 + c8;
                const float4 w0 = *(const float4*)(wr);
                const float4 w1 = *(const float4*)(wr + 4);
                float p  = dot4(w0, va)  + dot4(w1, vb);
                float p1 = dot4(w0, va1) + dot4(w1, vb1);
                p  = dpp_sum16(p);
                p1 = dpp_sum16(p1);
                if ((t & 15) == 15) {
                    U[g * 128 + i] = p;
                    if (g == 3) U[512 + i] = p1;
                }
            }
        }
        // state zero + per-step tables (all threads)
        for (int k = t; k < NCC2 + NC3P; k += 768) sh[k] = 0.f;
        for (int k = t; k < SS; k += 768) {
            shi[2504 + k] = c2_seq[b * SS + k];
            sh[3004 + k]  = D_emb[d_seq[b * SS + k]];
            shi[3104 + k] = r_seq[b * SS + k];
        }
        for (int k = t; k < SS; k += 768)
            reinterpret_cast<int4*>(shi + 2604)[k] = reinterpret_cast<const int4*>(c3_seq + b * SS * TT)[k];
        __syncthreads();
        if (t >= 64) return;

        float* C2s = sh;
        float* C3s = sh + NCC2;
        const float* u2 = sh + 3264;
        const float* u3 = sh + 3904;
        const float u2a0 = u2[t],        u2a1 = u2[64 + t];
        const float u2b0 = u2[128 + t],  u2b1 = u2[192 + t];
        const float u2c0 = u2[256 + t],  u2c1 = u2[320 + t];
        const float u2d00 = u2[384 + t], u2d01 = u2[448 + t];
        const float u2d10 = u2[512 + t], u2d11 = u2[576 + t];
        const float u3a0 = u3[t],        u3a1 = u3[64 + t];
        const float u3b0 = u3[128 + t],  u3b1 = u3[192 + t];
        const float u3c0 = u3[256 + t],  u3c1 = u3[320 + t];
        const float u3d00 = u3[384 + t], u3d01 = u3[448 + t];
        const float u3d10 = u3[512 + t], u3d11 = u3[576 + t];
        const float b2_0 = l2b1[t], b2_1 = l2b1[64 + t];
        const float w2_0 = l2W2[t], w2_1 = l2W2[64 + t];
        const float b3_0 = l3b1[t], b3_1 = l3b1[64 + t];
        const float w3_0 = l3W2[t], w3_1 = l3W2[64 + t];
        const float c2bias = l2b2[0], c3bias = l3b2[0];

        int  nc2 = shi[2504];
        int4 nc3 = reinterpret_cast<const int4*>(shi + 2604)[0];
        float ngam = sh[3004];
        int   nrr  = shi[3104];

        for (int s = 0; s < SS; ++s) {
            const int rs = b * SS + s;
            const int c2i = nc2;
            const int i0 = nc3.x, i1 = nc3.y, i2 = nc3.z, i3 = nc3.w;
            const float gamma = ngam;
            const int rr = nrr;
            if (s + 1 < SS) {
                nc2 = shi[2504 + s + 1];
                nc3 = reinterpret_cast<const int4*>(shi + 2604)[s + 1];
                ngam = sh[3004 + s + 1];
                nrr  = shi[3104 + s + 1];
            }

            const float beta2 = C2s[c2i];
            const bool k0 = (i0 != 0), k1 = (i1 != 0), k2 = (i2 != 0), k3 = (i3 != 0);
            const float m0 = k0 ? 1.f : 0.f, m1 = k1 ? 1.f : 0.f;
            const float m2 = k2 ? 1.f : 0.f, m3 = k3 ? 1.f : 0.f;
            const float bt0 = C3s[i0], bt1 = C3s[i1], bt2 = C3s[i2], bt3 = C3s[i3];
            const float msum = m0 + m1 + m2 + m3;
            const float b3bar = (bt0 * m0 + bt1 * m1 + bt2 * m2 + bt3 * m3) * fast_rcp(msum);

            const float ud20 = rr ? u2d10 : u2d00, ud21 = rr ? u2d11 : u2d01;
            const float ud30 = rr ? u3d10 : u3d00, ud31 = rr ? u3d11 : u3d01;

            float h20 = fmaf(beta2, u2a0, fmaf(b3bar, u2b0, fmaf(gamma, u2c0, ud20 + b2_0)));
            float h21 = fmaf(beta2, u2a1, fmaf(b3bar, u2b1, fmaf(gamma, u2c1, ud21 + b2_1)));
            float newc2 = dpp_sum64(fmaf(fmaxf(h20, 0.f), w2_0, fmaxf(h21, 0.f) * w2_1)) + c2bias;

            const float base30 = fmaf(beta2, u3a0, fmaf(gamma, u3c0, ud30 + b3_0));
            const float base31 = fmaf(beta2, u3a1, fmaf(gamma, u3c1, ud31 + b3_1));
            float ha, hb, q0, q1, q2, q3;
            ha = fmaf(bt0, u3b0, base30); hb = fmaf(bt0, u3b1, base31);
            q0 = dpp_sum64(fmaf(fmaxf(ha, 0.f), w3_0, fmaxf(hb, 0.f) * w3_1)) + c3bias;
            ha = fmaf(bt1, u3b0, base30); hb = fmaf(bt1, u3b1, base31);
            q1 = dpp_sum64(fmaf(fmaxf(ha, 0.f), w3_0, fmaxf(hb, 0.f) * w3_1)) + c3bias;
            ha = fmaf(bt2, u3b0, base30); hb = fmaf(bt2, u3b1, base31);
            q2 = dpp_sum64(fmaf(fmaxf(ha, 0.f), w3_0, fmaxf(hb, 0.f) * w3_1)) + c3bias;
            ha = fmaf(bt3, u3b0, base30); hb = fmaf(bt3, u3b1, base31);
            q3 = dpp_sum64(fmaf(fmaxf(ha, 0.f), w3_0, fmaxf(hb, 0.f) * w3_1)) + c3bias;

            float val0, val1, val2, val3;
            {
                float c = m0 + ((k1 && i1 == i0) ? 1.f : 0.f) + ((k2 && i2 == i0) ? 1.f : 0.f) + ((k3 && i3 == i0) ? 1.f : 0.f);
                float qs = (k0 ? q0 : 0.f) + ((k1 && i1 == i0) ? q1 : 0.f) + ((k2 && i2 == i0) ? q2 : 0.f) + ((k3 && i3 == i0) ? q3 : 0.f);
                val0 = bt0 * (1.f - c) + qs;
            }
            {
                float c = ((k0 && i0 == i1) ? 1.f : 0.f) + m1 + ((k2 && i2 == i1) ? 1.f : 0.f) + ((k3 && i3 == i1) ? 1.f : 0.f);
                float qs = ((k0 && i0 == i1) ? q0 : 0.f) + (k1 ? q1 : 0.f) + ((k2 && i2 == i1) ? q2 : 0.f) + ((k3 && i3 == i1) ? q3 : 0.f);
                val1 = bt1 * (1.f - c) + qs;
            }
            {
                float c = ((k0 && i0 == i2) ? 1.f : 0.f) + ((k1 && i1 == i2) ? 1.f : 0.f) + m2 + ((k3 && i3 == i2) ? 1.f : 0.f);
                float qs = ((k0 && i0 == i2) ? q0 : 0.f) + ((k1 && i1 == i2) ? q1 : 0.f) + (k2 ? q2 : 0.f) + ((k3 && i3 == i2) ? q3 : 0.f);
                val2 = bt2 * (1.f - c) + qs;
            }
            {
                float c = ((k0 && i0 == i3) ? 1.f : 0.f) + ((k1 && i1 == i3) ? 1.f : 0.f) + ((k2 && i2 == i3) ? 1.f : 0.f) + m3;
                float qs = ((k0 && i0 == i3) ? q0 : 0.f) + ((k1 && i1 == i3) ? q1 : 0.f) + ((k2 && i2 == i3) ? q2 : 0.f) + (k3 ? q3 : 0.f);
                val3 = bt3 * (1.f - c) + qs;
            }

            if (t == 63) {
                C2s[c2i] = newc2;
                if (k0) C3s[i0] = val0;
                if (k1) C3s[i1] = val1;
                if (k2) C3s[i2] = val2;
                if (k3) C3s[i3] = val3;
            }

            // snapshot store: this block's quarter of row (b,s)
            if (q == 0) {
                float* c2row = C2o + (size_t)rs * NCC2;
                const float4* src = reinterpret_cast<const float4*>(C2s);
                float4* dst = reinterpret_cast<float4*>(c2row);
                dst[t] = src[t];
                if (t < 61) dst[64 + t] = src[64 + t];
            } else {
                float* c3row = C3o + (size_t)rs * NC3P;
                const int lo = (q - 1) * 667;
                const int n = 667;
                int pre = (4 - (int)(((unsigned)(rs * NC3P + lo)) & 3)) & 3;
                if (pre > n) pre = n;
                if (t < pre) c3row[lo + t] = C3s[lo + t];
                const int st = lo + pre;
                const int rem = n - pre;
                const int nv = rem >> 2, tl = rem & 3;
                for (int i = t; i < nv; i += 64) {
                    const int d = st + 4 * i;
                    *reinterpret_cast<float4*>(c3row + d) =
                        make_float4(C3s[d], C3s[d + 1], C3s[d + 2], C3s[d + 3]);
                }
                if (t < tl) {
                    const int d = st + 4 * nv + t;
                    c3row[d] = C3s[d];
                }
            }
        }
    }
}

// ---------------------------------------------------------------------------
// k_alpha: alpha = MLP1(h). 200 blocks x 256 threads, 16 rows per block.
__global__ __launch_bounds__(256) void k_alpha(const float* __restrict__ h_seq,
                                               const float* __restrict__ W1,
                                               const float* __restrict__ b1,
                                               const float* __restrict__ W2,
                                               const float* __restrict__ b2,
                                               float* __restrict__ alpha)
{
    __shared__ __align__(16) float sl[22560];
    const int t = threadIdx.x;
    const int base = blockIdx.x * 16;

    float4* hl4 = reinterpret_cast<float4*>(sl);
    const float4* hg = reinterpret_cast<const float4*>(h_seq + (size_t)base * DD);
    for (int i = t; i < 512; i += 256) hl4[i] = hg[i];

    float4* wl4 = reinterpret_cast<float4*>(sl + 6144);
    const float4* wg = reinterpret_cast<const float4*>(W1);
    for (int g = t; g < 4096; g += 256) {
        const int ch = g >> 5, k4 = g & 31;
        wl4[ch * 32 + (k4 ^ (ch & 31))] = wg[g];
    }
    __syncthreads();

    const int ch = t & 127, half = t >> 7;
    float acc[16];
#pragma unroll
    for (int r = 0; r < 16; ++r) acc[r] = 0.f;
#pragma unroll
    for (int kk = 0; kk < 16; ++kk) {
        const int k4 = half * 16 + kk;
        const float4 w = wl4[ch * 32 + (k4 ^ (ch & 31))];
#pragma unroll
        for (int r = 0; r < 16; ++r) {
            const float4 hv = hl4[r * 32 + k4];
            acc[r] = fmaf(w.x, hv.x, fmaf(w.y, hv.y, fmaf(w.z, hv.z, fmaf(w.w, hv.w, acc[r]))));
        }
    }
#pragma unroll
    for (int r = 0; r < 16; ++r) sl[2048 + r * 256 + t] = acc[r];
    __syncthreads();
    if (t < 128) {
        const float b1v = b1[t], w2v = W2[t];
#pragma unroll
        for (int r = 0; r < 16; ++r) {
            float v = fmaxf(sl[2048 + r * 256 + t] + sl[2048 + r * 256 + 128 + t] + b1v, 0.f) * w2v;
            v = dpp_sum64(v);
            if ((t & 63) == 63) sl[22528 + r * 2 + (t >> 6)] = v;
        }
    }
    __syncthreads();
    if (t < 16) alpha[base + t] = sl[22528 + 2 * t] + sl[22528 + 2 * t + 1] + b2[0];
}

// ---------------------------------------------------------------------------
extern "C" void kernel_launch(void* const* d_in, const int* in_sizes, int n_in,
                              void* d_out, int out_size, void* d_ws, size_t ws_size,
                              hipStream_t stream)
{
    (void)in_sizes; (void)n_in; (void)out_size; (void)d_ws; (void)ws_size;
    const int*   c2_seq = (const int*)d_in[0];
    const int*   c3_seq = (const int*)d_in[1];
    const int*   d_seq  = (const int*)d_in[2];
    const int*   r_seq  = (const int*)d_in[3];
    const float* D_emb  = (const float*)d_in[4];
    const float* Remb   = (const float*)d_in[5];
    const float* v_c2   = (const float*)d_in[6];
    const float* v_c3   = (const float*)d_in[7];
    const float* v_d    = (const float*)d_in[8];
    const float* W_ih   = (const float*)d_in[9];
    const float* W_hh   = (const float*)d_in[10];
    const float* b_ih   = (const float*)d_in[11];
    const float* b_hh   = (const float*)d_in[12];
    const float* l1W1   = (const float*)d_in[13];
    const float* l1b1   = (const float*)d_in[14];
    const float* l1W2   = (const float*)d_in[15];
    const float* l1b2   = (const float*)d_in[16];
    const float* l2W1   = (const float*)d_in[17];
    const float* l2b1   = (const float*)d_in[18];
    const float* l2W2   = (const float*)d_in[19];
    const float* l2b2   = (const float*)d_in[20];
    const float* l3W1   = (const float*)d_in[21];
    const float* l3b1   = (const float*)d_in[22];
    const float* l3W2   = (const float*)d_in[23];
    const float* l3b2   = (const float*)d_in[24];

    float* out   = (float*)d_out;
    float* alpha = out;                 // [B,S]
    float* h_out = out + 3200;          // [B,S,128]
    float* C2o   = out + 412800;        // [B,S,500]
    float* C3o   = out + 2012800;       // [B,S,2001]

    k_main<<<BB + 4 * BB, 768, 0, stream>>>(c2_seq, c3_seq, d_seq, r_seq, D_emb, Remb,
                                            v_c2, v_c3, v_d,
                                            W_ih, W_hh, b_ih, b_hh,
                                            l2W1, l2b1, l2W2, l2b2,
                                            l3W1, l3b1, l3W2, l3b2,
                                            h_out, C2o, C3o);
    k_alpha<<<200, 256, 0, stream>>>(h_out, l1W1, l1b1, l1W2, l1b2, alpha);
}